// Round 1
// baseline (354.816 us; speedup 1.0000x reference)
//
#include <hip/hip_runtime.h>
#include <stdint.h>

#define IN_C   128
#define OUT_C  128
#define KTOT   1152      // IN_C*3*3
#define NG     8
#define NW     8
#define NB     8
#define HH     56
#define WWID   56
#define NPIX   3136
#define PPAD   3200
#define MTOT   1024      // OUT_C*NW

typedef __attribute__((ext_vector_type(8))) short short8;
typedef __attribute__((ext_vector_type(8))) unsigned short ushort8;
typedef __attribute__((ext_vector_type(4))) float f32x4;

__device__ __forceinline__ unsigned short f2bf(float f) {
    unsigned u = __float_as_uint(f);
    u += 0x7FFF + ((u >> 16) & 1);          // round-to-nearest-even
    return (unsigned short)(u >> 16);
}

__device__ __forceinline__ void cp16(const unsigned short* g, unsigned short* l) {
    __builtin_amdgcn_global_load_lds(
        (const __attribute__((address_space(1))) unsigned int*)g,
        (__attribute__((address_space(3))) unsigned int*)l,
        16, 0, 0);
}

// ---------- 1) global average pool: x_se[b,c] = mean_hw inputs ----------
__global__ __launch_bounds__(256) void gap_kernel(const float* __restrict__ in,
                                                  float* __restrict__ xse) {
    const int bc = blockIdx.x;                       // 0..1023
    const float* src = in + (size_t)bc * NPIX;
    float s = 0.f;
    for (int i = threadIdx.x; i < NPIX / 4; i += 256) {
        float4 v = ((const float4*)src)[i];
        s += v.x + v.y + v.z + v.w;
    }
    #pragma unroll
    for (int off = 32; off; off >>= 1) s += __shfl_down(s, off);
    __shared__ float ws4[4];
    if ((threadIdx.x & 63) == 0) ws4[threadIdx.x >> 6] = s;
    __syncthreads();
    if (threadIdx.x == 0)
        xse[bc] = (ws4[0] + ws4[1] + ws4[2] + ws4[3]) * (1.0f / (float)NPIX);
}

// ---------- 2) routing: r[b,gj] = 2*sigmoid(xse@W^T + b)/NW ----------
__global__ __launch_bounds__(64) void route_kernel(const float* __restrict__ xse,
                                                   const float* __restrict__ rw,
                                                   const float* __restrict__ rb,
                                                   float* __restrict__ r) {
    const int b = blockIdx.x;
    const int gj = threadIdx.x;                      // 0..63
    __shared__ float xs[IN_C];
    xs[gj] = xse[b * IN_C + gj];
    xs[gj + 64] = xse[b * IN_C + 64 + gj];
    __syncthreads();
    float acc = rb[gj];
    #pragma unroll 8
    for (int c = 0; c < IN_C; c++) acc += xs[c] * rw[gj * IN_C + c];
    r[b * 64 + gj] = 0.25f / (1.0f + expf(-acc));    // 2*sigmoid/8
}

// ---------- 3) templates -> bf16, A[m=o*8+j][k] = T[(o*K+k)*8+j] ----------
__global__ __launch_bounds__(256) void tconv_kernel(const float* __restrict__ T,
                                                    unsigned short* __restrict__ Abf) {
    const int id = blockIdx.x * 256 + threadIdx.x;   // 0..147455 (exact)
    const int m = id / 144;
    const int kc = id - m * 144;
    const int o = m >> 3, j = m & 7;
    const int k0 = kc * 8;
    ushort8 v;
    #pragma unroll
    for (int i = 0; i < 8; i++)
        v[i] = f2bf(T[((size_t)(o * KTOT + k0 + i)) * 8 + j]);
    *(ushort8*)&Abf[(size_t)m * KTOT + k0] = v;
}

// ---------- 4) im2col -> bf16 patches[b][p][k] (k contiguous, P padded) ----------
__global__ __launch_bounds__(256) void im2col_kernel(const float* __restrict__ in,
                                                     unsigned short* __restrict__ Pch) {
    const int b = blockIdx.y;
    const int pg = blockIdx.x;                       // 16 pixels per block
    for (int ci = threadIdx.x; ci < 16 * 144; ci += 256) {
        int pl = ci / 144, kc = ci - pl * 144;
        int p = pg * 16 + pl;
        int y = p / WWID, x = p - y * WWID;
        ushort8 v;
        #pragma unroll
        for (int i = 0; i < 8; i++) {
            int k = kc * 8 + i;
            int c = k / 9, rr = k - c * 9;
            int kh = rr / 3, kw = rr - kh * 3;
            int yy = y + kh - 1, xx = x + kw - 1;
            float val = 0.f;
            if (p < NPIX && yy >= 0 && yy < HH && xx >= 0 && xx < WWID)
                val = in[((size_t)b * IN_C + c) * NPIX + yy * WWID + xx];
            v[i] = f2bf(val);
        }
        *(ushort8*)&Pch[((size_t)b * PPAD + p) * KTOT + kc * 8] = v;
    }
}

// ---------- 5) s[b][p][j] = sum_g probs[b,g,p] * r[b,g*8+j] ----------
__global__ __launch_bounds__(256) void s_kernel(const float* __restrict__ Alpha,
                                                const int* __restrict__ mask,
                                                const float* __restrict__ r,
                                                const int* __restrict__ use_alpha,
                                                float* __restrict__ Sws) {
    const int b = blockIdx.y;
    const int p = blockIdx.x * 256 + threadIdx.x;
    __shared__ float rsh[64];
    if (threadIdx.x < 64) rsh[threadIdx.x] = r[b * 64 + threadIdx.x];
    __syncthreads();
    if (p >= PPAD) return;
    float sj[8] = {0, 0, 0, 0, 0, 0, 0, 0};
    if (p < NPIX) {
        float pr[8];
        if (use_alpha[0]) {
            float a[8], m = -1e30f;
            #pragma unroll
            for (int g = 0; g < 8; g++) {
                a[g] = Alpha[((size_t)(b * NG + g)) * NPIX + p];
                m = fmaxf(m, a[g]);
            }
            float sum = 0.f;
            #pragma unroll
            for (int g = 0; g < 8; g++) { pr[g] = expf(a[g] - m); sum += pr[g]; }
            float inv = 1.f / sum;
            #pragma unroll
            for (int g = 0; g < 8; g++) pr[g] *= inv;
        } else {
            int mg = mask[(size_t)b * NPIX + p];
            #pragma unroll
            for (int g = 0; g < 8; g++) pr[g] = (g == mg) ? 1.f : 0.f;
        }
        #pragma unroll
        for (int g = 0; g < 8; g++)
            #pragma unroll
            for (int j = 0; j < 8; j++) sj[j] += pr[g] * rsh[g * 8 + j];
    }
    float* dst = Sws + ((size_t)b * PPAD + p) * 8;
    *(f32x4*)dst = (f32x4){sj[0], sj[1], sj[2], sj[3]};
    *(f32x4*)(dst + 4) = (f32x4){sj[4], sj[5], sj[6], sj[7]};
}

// ---------- 6) main GEMM + blend epilogue ----------
// Z[m][p] = sum_k A[m][k]*patches[b][p][k]; out[b,o,p] = sum_j s[b,j,p]*Z[o*8+j][p] + bias[o]
// Block: 128x128 C-tile, BK=32, 4 waves of 64x64, mfma_f32_16x16x32_bf16.
// LDS layout: chunk-interleaved [q][row][8] (q = k-octet 0..3) so global_load_lds
// (wave-uniform base + lane*16) and ds_read_b128 frag reads (2-way banks = free) both work.
__global__ __launch_bounds__(256) void gemm_kernel(const unsigned short* __restrict__ Abf,
                                                   const unsigned short* __restrict__ Pch,
                                                   const float* __restrict__ Sws,
                                                   const float* __restrict__ bias,
                                                   float* __restrict__ out) {
    __shared__ __align__(16) unsigned short Ash[512 * 8];   // 8 KB
    __shared__ __align__(16) unsigned short Bsh[512 * 8];   // 8 KB
    const int tid = threadIdx.x;
    const int wv = tid >> 6, ln = tid & 63;
    const int lq = ln >> 4, lr = ln & 15;
    const int wrow = wv >> 1, wcol = wv & 1;
    const int nt = blockIdx.x, mt = blockIdx.y, b = blockIdx.z;

    f32x4 acc[4][4];
    #pragma unroll
    for (int i = 0; i < 4; i++)
        #pragma unroll
        for (int j = 0; j < 4; j++) acc[i][j] = (f32x4){0.f, 0.f, 0.f, 0.f};

    // staging: chunk = issue*256 + tid; LDS image linear in chunk order
    const int c0 = tid, c1 = 256 + tid;
    const int q0 = c0 >> 7, r0 = c0 & 127;
    const int q1 = c1 >> 7, r1 = c1 & 127;
    const unsigned short* ga0 = Abf + (size_t)(mt * 128 + r0) * KTOT + q0 * 8;
    const unsigned short* ga1 = Abf + (size_t)(mt * 128 + r1) * KTOT + q1 * 8;
    const unsigned short* gb0 = Pch + ((size_t)b * PPAD + nt * 128 + r0) * KTOT + q0 * 8;
    const unsigned short* gb1 = Pch + ((size_t)b * PPAD + nt * 128 + r1) * KTOT + q1 * 8;
    unsigned short* la0 = &Ash[(wv * 64) * 8];
    unsigned short* la1 = &Ash[(256 + wv * 64) * 8];
    unsigned short* lb0 = &Bsh[(wv * 64) * 8];
    unsigned short* lb1 = &Bsh[(256 + wv * 64) * 8];

    for (int kk = 0; kk < KTOT; kk += 32) {
        cp16(ga0 + kk, la0);
        cp16(ga1 + kk, la1);
        cp16(gb0 + kk, lb0);
        cp16(gb1 + kk, lb1);
        __syncthreads();   // drains vmcnt -> LDS tiles complete

        short8 af[4], bfr[4];
        #pragma unroll
        for (int tm = 0; tm < 4; tm++)
            af[tm] = *(const short8*)&Ash[((lq << 7) + wrow * 64 + tm * 16 + lr) * 8];
        #pragma unroll
        for (int tn = 0; tn < 4; tn++)
            bfr[tn] = *(const short8*)&Bsh[((lq << 7) + wcol * 64 + tn * 16 + lr) * 8];
        #pragma unroll
        for (int tm = 0; tm < 4; tm++)
            #pragma unroll
            for (int tn = 0; tn < 4; tn++)
                acc[tm][tn] = __builtin_amdgcn_mfma_f32_16x16x32_bf16(
                    af[tm], bfr[tn], acc[tm][tn], 0, 0, 0);
        __syncthreads();   // before next stage overwrites LDS
    }

    // epilogue: rows m = ...+lq*4+reg -> j = (lq&1)*4+reg, o_off = lq>>1
    const int j0 = (lq & 1) * 4;
    const int oo = lq >> 1;
    #pragma unroll
    for (int tm = 0; tm < 4; tm++) {
        const int o = mt * 16 + wrow * 8 + tm * 2 + oo;
        const float bo = bias[o];
        #pragma unroll
        for (int tn = 0; tn < 4; tn++) {
            const int p = nt * 128 + wcol * 64 + tn * 16 + lr;
            const f32x4 sv = *(const f32x4*)&Sws[((size_t)b * PPAD + p) * 8 + j0];
            const f32x4 a = acc[tm][tn];
            float part = a.x * sv.x + a.y * sv.y + a.z * sv.z + a.w * sv.w;
            float tot = part + __shfl_xor(part, 16);   // combine j0=0 with j0=4 half
            if ((lq & 1) == 0 && p < NPIX)
                out[((size_t)b * OUT_C + o) * NPIX + p] = tot + bo;
        }
    }
}

extern "C" void kernel_launch(void* const* d_in, const int* in_sizes, int n_in,
                              void* d_out, int out_size, void* d_ws, size_t ws_size,
                              hipStream_t stream) {
    const float* inputs = (const float*)d_in[0];
    const int*   mask   = (const int*)d_in[1];
    const float* Alpha  = (const float*)d_in[2];
    const float* wtmpl  = (const float*)d_in[3];
    const float* rw     = (const float*)d_in[4];
    const float* rb     = (const float*)d_in[5];
    const float* bias   = (const float*)d_in[6];
    const int*   ua     = (const int*)d_in[7];
    float* out = (float*)d_out;

    char* ws = (char*)d_ws;
    unsigned short* Pch = (unsigned short*)ws;                   // 8*3200*1152*2 = 58,982,400
    unsigned short* Abf = (unsigned short*)(ws + 58982400);      // 1024*1152*2  =  2,359,296
    float*          Sws = (float*)(ws + 61341696);               // 8*3200*8*4   =    819,200
    float*          xse = (float*)(ws + 62160896);               // 1024*4
    float*          rr  = (float*)(ws + 62164992);               // 512*4

    gap_kernel<<<NB * IN_C, 256, 0, stream>>>(inputs, xse);
    route_kernel<<<NB, 64, 0, stream>>>(xse, rw, rb, rr);
    tconv_kernel<<<576, 256, 0, stream>>>(wtmpl, Abf);
    im2col_kernel<<<dim3(PPAD / 16, NB), 256, 0, stream>>>(inputs, Pch);
    s_kernel<<<dim3(13, NB), 256, 0, stream>>>(Alpha, mask, rr, ua, Sws);
    gemm_kernel<<<dim3(PPAD / 128, MTOT / 128, NB), 256, 0, stream>>>(Abf, Pch, Sws, bias, out);
}

// Round 2
// 282.086 us; speedup vs baseline: 1.2578x; 1.2578x over previous
//
#include <hip/hip_runtime.h>
#include <stdint.h>

#define IN_C   128
#define OUT_C  128
#define KTOT   1152      // IN_C*3*3
#define NG     8
#define NW     8
#define NB     8
#define HH     56
#define WWID   56
#define NPIX   3136
#define PPAD   3200
#define MTOT   1024      // OUT_C*NW

// k-order is SPATIAL-MAJOR: k' = s*128 + c, s = kh*3+kw. A-repack (tconv) and
// im2col both use it; the GEMM is order-agnostic.

typedef __attribute__((ext_vector_type(8))) short short8;
typedef __attribute__((ext_vector_type(8))) unsigned short ushort8;
typedef __attribute__((ext_vector_type(4))) float f32x4;

__device__ __forceinline__ unsigned short f2bf(float f) {
    unsigned u = __float_as_uint(f);
    u += 0x7FFF + ((u >> 16) & 1);          // round-to-nearest-even
    return (unsigned short)(u >> 16);
}

__device__ __forceinline__ void cp16(const unsigned short* g, unsigned short* l) {
    __builtin_amdgcn_global_load_lds(
        (const __attribute__((address_space(1))) unsigned int*)g,
        (__attribute__((address_space(3))) unsigned int*)l,
        16, 0, 0);
}

// ---------- 1) global average pool ----------
__global__ __launch_bounds__(256) void gap_kernel(const float* __restrict__ in,
                                                  float* __restrict__ xse) {
    const int bc = blockIdx.x;                       // 0..1023
    const float* src = in + (size_t)bc * NPIX;
    float s = 0.f;
    for (int i = threadIdx.x; i < NPIX / 4; i += 256) {
        float4 v = ((const float4*)src)[i];
        s += v.x + v.y + v.z + v.w;
    }
    #pragma unroll
    for (int off = 32; off; off >>= 1) s += __shfl_down(s, off);
    __shared__ float ws4[4];
    if ((threadIdx.x & 63) == 0) ws4[threadIdx.x >> 6] = s;
    __syncthreads();
    if (threadIdx.x == 0)
        xse[bc] = (ws4[0] + ws4[1] + ws4[2] + ws4[3]) * (1.0f / (float)NPIX);
}

// ---------- 2) routing: r[b,gj] = 2*sigmoid(xse@W^T + b)/NW ----------
__global__ __launch_bounds__(64) void route_kernel(const float* __restrict__ xse,
                                                   const float* __restrict__ rw,
                                                   const float* __restrict__ rb,
                                                   float* __restrict__ r) {
    const int b = blockIdx.x;
    const int gj = threadIdx.x;                      // 0..63
    __shared__ float xs[IN_C];
    xs[gj] = xse[b * IN_C + gj];
    xs[gj + 64] = xse[b * IN_C + 64 + gj];
    __syncthreads();
    float acc = rb[gj];
    #pragma unroll 8
    for (int c = 0; c < IN_C; c++) acc += xs[c] * rw[gj * IN_C + c];
    r[b * 64 + gj] = 0.25f / (1.0f + expf(-acc));    // 2*sigmoid/8
}

// ---------- 3) templates -> bf16, A[m=o*8+j][k'=s*128+c] = T[(o*1152+c*9+s)*8+j] ----------
__global__ __launch_bounds__(256) void tconv_kernel(const float* __restrict__ T,
                                                    unsigned short* __restrict__ Abf) {
    const int id = blockIdx.x * 256 + threadIdx.x;   // 0..147455 exact (1024 m * 144 kc)
    const int m = id / 144;
    const int kc = id - m * 144;
    const int o = m >> 3, j = m & 7;
    const int s = kc >> 4;
    const int c0 = (kc & 15) << 3;
    ushort8 v;
    #pragma unroll
    for (int i = 0; i < 8; i++)
        v[i] = f2bf(T[((size_t)(o * KTOT + (c0 + i) * 9 + s)) * 8 + j]);
    *(ushort8*)&Abf[(size_t)m * KTOT + s * 128 + c0] = v;
}

// ---------- 4) im2col v2: transpose-through-LDS, spatial-major k ----------
// Block (yt, s, b): 2 output rows (112 px) x 128 c for one spatial offset s.
// Phase 1: coalesced-ish masked float4 reads of shifted input -> bf16 -> LDS [c][pp^swz].
// Phase 2: k-chunk (8 c) packing from LDS -> coalesced 16B global stores.
__global__ __launch_bounds__(256) void im2col_kernel(const float* __restrict__ in,
                                                     unsigned short* __restrict__ Pch) {
    __shared__ unsigned short tile[128 * 128];       // 32 KB, [c][128]
    const int t  = threadIdx.x;
    const int yt = blockIdx.x;                       // 0..27  -> rows 2*yt, 2*yt+1
    const int s  = blockIdx.y;                       // 0..8
    const int b  = blockIdx.z;
    const int kh = s / 3, kw = s - kh * 3;
    const int y0 = yt * 2;

    // phase 1: 3584 float4-units = 128 c * 2 y * 14 x4
    #pragma unroll
    for (int it = 0; it < 14; it++) {
        const int f = it * 256 + t;
        const int c = f / 28;
        const int rem = f - c * 28;
        const int y = rem / 14;
        const int x4 = rem - y * 14;
        const int yy = y0 + y + kh - 1;
        const int yyc = min(max(yy, 0), HH - 1);
        const bool yok = (yy >= 0) & (yy < HH);
        const float* row = in + ((size_t)(b * IN_C + c)) * NPIX + yyc * WWID;
        unsigned short bf[4];
        #pragma unroll
        for (int e = 0; e < 4; e++) {
            const int xs = x4 * 4 + e + kw - 1;
            const int xc = min(max(xs, 0), WWID - 1);
            float v = row[xc];
            v = (yok & (xs >= 0) & (xs < WWID)) ? v : 0.f;
            bf[e] = f2bf(v);
        }
        const int ppb = (y * WWID + x4 * 4) ^ (((c >> 3) & 15) << 2);
        uint2 pk;
        pk.x = (unsigned)bf[0] | ((unsigned)bf[1] << 16);
        pk.y = (unsigned)bf[2] | ((unsigned)bf[3] << 16);
        *(uint2*)&tile[c * 128 + ppb] = pk;
    }
    __syncthreads();

    // phase 2: 1792 chunks = 112 pp * 16 octs; lane-major over octs -> coalesced stores
    #pragma unroll
    for (int it = 0; it < 7; it++) {
        const int ch = it * 256 + t;
        const int oct = ch & 15;
        const int pp = ch >> 4;
        const int sw = oct << 2;
        ushort8 v;
        #pragma unroll
        for (int i = 0; i < 8; i++)
            v[i] = tile[(oct * 8 + i) * 128 + (pp ^ sw)];
        const int p = yt * 112 + pp;
        *(ushort8*)&Pch[((size_t)b * PPAD + p) * KTOT + s * 128 + oct * 8] = v;
    }
}

// ---------- 5) s[b][p][j] = sum_g probs[b,g,p] * r[b,g*8+j] ----------
__global__ __launch_bounds__(256) void s_kernel(const float* __restrict__ Alpha,
                                                const int* __restrict__ mask,
                                                const float* __restrict__ r,
                                                const int* __restrict__ use_alpha,
                                                float* __restrict__ Sws) {
    const int b = blockIdx.y;
    const int p = blockIdx.x * 256 + threadIdx.x;
    __shared__ float rsh[64];
    if (threadIdx.x < 64) rsh[threadIdx.x] = r[b * 64 + threadIdx.x];
    __syncthreads();
    if (p >= PPAD) return;
    float sj[8] = {0, 0, 0, 0, 0, 0, 0, 0};
    if (p < NPIX) {
        float pr[8];
        if (use_alpha[0]) {
            float a[8], m = -1e30f;
            #pragma unroll
            for (int g = 0; g < 8; g++) {
                a[g] = Alpha[((size_t)(b * NG + g)) * NPIX + p];
                m = fmaxf(m, a[g]);
            }
            float sum = 0.f;
            #pragma unroll
            for (int g = 0; g < 8; g++) { pr[g] = expf(a[g] - m); sum += pr[g]; }
            float inv = 1.f / sum;
            #pragma unroll
            for (int g = 0; g < 8; g++) pr[g] *= inv;
        } else {
            int mg = mask[(size_t)b * NPIX + p];
            #pragma unroll
            for (int g = 0; g < 8; g++) pr[g] = (g == mg) ? 1.f : 0.f;
        }
        #pragma unroll
        for (int g = 0; g < 8; g++)
            #pragma unroll
            for (int j = 0; j < 8; j++) sj[j] += pr[g] * rsh[g * 8 + j];
    }
    float* dst = Sws + ((size_t)b * PPAD + p) * 8;
    *(f32x4*)dst = (f32x4){sj[0], sj[1], sj[2], sj[3]};
    *(f32x4*)(dst + 4) = (f32x4){sj[4], sj[5], sj[6], sj[7]};
}

// ---------- 6) main GEMM + blend epilogue ----------
// grid.x = mt (fastest) so 8 consecutive blocks share one B-strip -> L2 reuse.
__global__ __launch_bounds__(256) void gemm_kernel(const unsigned short* __restrict__ Abf,
                                                   const unsigned short* __restrict__ Pch,
                                                   const float* __restrict__ Sws,
                                                   const float* __restrict__ bias,
                                                   float* __restrict__ out) {
    __shared__ __align__(16) unsigned short Ash[512 * 8];   // 8 KB
    __shared__ __align__(16) unsigned short Bsh[512 * 8];   // 8 KB
    const int tid = threadIdx.x;
    const int wv = tid >> 6, ln = tid & 63;
    const int lq = ln >> 4, lr = ln & 15;
    const int wrow = wv >> 1, wcol = wv & 1;
    const int mt = blockIdx.x, nt = blockIdx.y, b = blockIdx.z;

    f32x4 acc[4][4];
    #pragma unroll
    for (int i = 0; i < 4; i++)
        #pragma unroll
        for (int j = 0; j < 4; j++) acc[i][j] = (f32x4){0.f, 0.f, 0.f, 0.f};

    const int c0 = tid, c1 = 256 + tid;
    const int q0 = c0 >> 7, r0 = c0 & 127;
    const int q1 = c1 >> 7, r1 = c1 & 127;
    // clamp B rows into the valid region (pad rows p>=NPIX are never written)
    const int br0 = min(nt * 128 + r0, NPIX - 1);
    const int br1 = min(nt * 128 + r1, NPIX - 1);
    const unsigned short* ga0 = Abf + (size_t)(mt * 128 + r0) * KTOT + q0 * 8;
    const unsigned short* ga1 = Abf + (size_t)(mt * 128 + r1) * KTOT + q1 * 8;
    const unsigned short* gb0 = Pch + ((size_t)b * PPAD + br0) * KTOT + q0 * 8;
    const unsigned short* gb1 = Pch + ((size_t)b * PPAD + br1) * KTOT + q1 * 8;
    unsigned short* la0 = &Ash[(wv * 64) * 8];
    unsigned short* la1 = &Ash[(256 + wv * 64) * 8];
    unsigned short* lb0 = &Bsh[(wv * 64) * 8];
    unsigned short* lb1 = &Bsh[(256 + wv * 64) * 8];

    for (int kk = 0; kk < KTOT; kk += 32) {
        cp16(ga0 + kk, la0);
        cp16(ga1 + kk, la1);
        cp16(gb0 + kk, lb0);
        cp16(gb1 + kk, lb1);
        __syncthreads();

        short8 af[4], bfr[4];
        #pragma unroll
        for (int tm = 0; tm < 4; tm++)
            af[tm] = *(const short8*)&Ash[((lq << 7) + wrow * 64 + tm * 16 + lr) * 8];
        #pragma unroll
        for (int tn = 0; tn < 4; tn++)
            bfr[tn] = *(const short8*)&Bsh[((lq << 7) + wcol * 64 + tn * 16 + lr) * 8];
        #pragma unroll
        for (int tm = 0; tm < 4; tm++)
            #pragma unroll
            for (int tn = 0; tn < 4; tn++)
                acc[tm][tn] = __builtin_amdgcn_mfma_f32_16x16x32_bf16(
                    af[tm], bfr[tn], acc[tm][tn], 0, 0, 0);
        __syncthreads();
    }

    // epilogue: rows m -> j = (lq&1)*4+reg, o_off = lq>>1
    const int j0 = (lq & 1) * 4;
    const int oo = lq >> 1;
    #pragma unroll
    for (int tm = 0; tm < 4; tm++) {
        const int o = mt * 16 + wrow * 8 + tm * 2 + oo;
        const float bo = bias[o];
        #pragma unroll
        for (int tn = 0; tn < 4; tn++) {
            const int p = nt * 128 + wcol * 64 + tn * 16 + lr;
            const f32x4 sv = *(const f32x4*)&Sws[((size_t)b * PPAD + p) * 8 + j0];
            const f32x4 a = acc[tm][tn];
            float part = a.x * sv.x + a.y * sv.y + a.z * sv.z + a.w * sv.w;
            float tot = part + __shfl_xor(part, 16);
            if ((lq & 1) == 0 && p < NPIX)
                out[((size_t)b * OUT_C + o) * NPIX + p] = tot + bo;
        }
    }
}

extern "C" void kernel_launch(void* const* d_in, const int* in_sizes, int n_in,
                              void* d_out, int out_size, void* d_ws, size_t ws_size,
                              hipStream_t stream) {
    const float* inputs = (const float*)d_in[0];
    const int*   mask   = (const int*)d_in[1];
    const float* Alpha  = (const float*)d_in[2];
    const float* wtmpl  = (const float*)d_in[3];
    const float* rw     = (const float*)d_in[4];
    const float* rb     = (const float*)d_in[5];
    const float* bias   = (const float*)d_in[6];
    const int*   ua     = (const int*)d_in[7];
    float* out = (float*)d_out;

    char* ws = (char*)d_ws;
    unsigned short* Pch = (unsigned short*)ws;                   // 8*3200*1152*2 = 58,982,400
    unsigned short* Abf = (unsigned short*)(ws + 58982400);      // 1024*1152*2  =  2,359,296
    float*          Sws = (float*)(ws + 61341696);               // 8*3200*8*4   =    819,200
    float*          xse = (float*)(ws + 62160896);               // 1024*4
    float*          rr  = (float*)(ws + 62164992);               // 512*4

    gap_kernel<<<NB * IN_C, 256, 0, stream>>>(inputs, xse);
    route_kernel<<<NB, 64, 0, stream>>>(xse, rw, rb, rr);
    tconv_kernel<<<576, 256, 0, stream>>>(wtmpl, Abf);
    im2col_kernel<<<dim3(28, 9, NB), 256, 0, stream>>>(inputs, Pch);
    s_kernel<<<dim3(13, NB), 256, 0, stream>>>(Alpha, mask, rr, ua, Sws);
    gemm_kernel<<<dim3(MTOT / 128, PPAD / 128, NB), 256, 0, stream>>>(Abf, Pch, Sws, bias, out);
}

// Round 3
// 269.068 us; speedup vs baseline: 1.3187x; 1.0484x over previous
//
#include <hip/hip_runtime.h>
#include <stdint.h>

#define IN_C   128
#define OUT_C  128
#define KTOT   1152      // IN_C*3*3
#define NG     8
#define NW     8
#define NB     8
#define HH     56
#define WWID   56
#define NPIX   3136
#define PPAD   3200
#define MTOT   1024      // OUT_C*NW

// k-order is SPATIAL-MAJOR: k' = s*128 + c, s = kh*3+kw.

typedef __attribute__((ext_vector_type(8))) short short8;
typedef __attribute__((ext_vector_type(8))) unsigned short ushort8;
typedef __attribute__((ext_vector_type(4))) float f32x4;

__device__ __forceinline__ unsigned short f2bf(float f) {
    unsigned u = __float_as_uint(f);
    u += 0x7FFF + ((u >> 16) & 1);          // round-to-nearest-even
    return (unsigned short)(u >> 16);
}

__device__ __forceinline__ void cp16(const unsigned short* g, unsigned short* l) {
    __builtin_amdgcn_global_load_lds(
        (const __attribute__((address_space(1))) unsigned int*)g,
        (__attribute__((address_space(3))) unsigned int*)l,
        16, 0, 0);
}

// ---------- 1) global average pool ----------
__global__ __launch_bounds__(256) void gap_kernel(const float* __restrict__ in,
                                                  float* __restrict__ xse) {
    const int bc = blockIdx.x;                       // 0..1023
    const float* src = in + (size_t)bc * NPIX;
    float s = 0.f;
    for (int i = threadIdx.x; i < NPIX / 4; i += 256) {
        float4 v = ((const float4*)src)[i];
        s += v.x + v.y + v.z + v.w;
    }
    #pragma unroll
    for (int off = 32; off; off >>= 1) s += __shfl_down(s, off);
    __shared__ float ws4[4];
    if ((threadIdx.x & 63) == 0) ws4[threadIdx.x >> 6] = s;
    __syncthreads();
    if (threadIdx.x == 0)
        xse[bc] = (ws4[0] + ws4[1] + ws4[2] + ws4[3]) * (1.0f / (float)NPIX);
}

// ---------- 2) routing: r[b,gj] = 2*sigmoid(xse@W^T + b)/NW ----------
__global__ __launch_bounds__(64) void route_kernel(const float* __restrict__ xse,
                                                   const float* __restrict__ rw,
                                                   const float* __restrict__ rb,
                                                   float* __restrict__ r) {
    const int b = blockIdx.x;
    const int gj = threadIdx.x;                      // 0..63
    __shared__ float xs[IN_C];
    xs[gj] = xse[b * IN_C + gj];
    xs[gj + 64] = xse[b * IN_C + 64 + gj];
    __syncthreads();
    float acc = rb[gj];
    #pragma unroll 8
    for (int c = 0; c < IN_C; c++) acc += xs[c] * rw[gj * IN_C + c];
    r[b * 64 + gj] = 0.25f / (1.0f + expf(-acc));    // 2*sigmoid/8
}

// ---------- 3) templates -> bf16, A[m=o*8+j][k'=s*128+c] = T[(o*1152+c*9+s)*8+j] ----------
__global__ __launch_bounds__(256) void tconv_kernel(const float* __restrict__ T,
                                                    unsigned short* __restrict__ Abf) {
    const int id = blockIdx.x * 256 + threadIdx.x;   // 0..147455 exact (1024 m * 144 kc)
    const int m = id / 144;
    const int kc = id - m * 144;
    const int o = m >> 3, j = m & 7;
    const int s = kc >> 4;
    const int c0 = (kc & 15) << 3;
    ushort8 v;
    #pragma unroll
    for (int i = 0; i < 8; i++)
        v[i] = f2bf(T[((size_t)(o * KTOT + (c0 + i) * 9 + s)) * 8 + j]);
    *(ushort8*)&Abf[(size_t)m * KTOT + s * 128 + c0] = v;
}

// ---------- 4) im2col v2: transpose-through-LDS, spatial-major k ----------
__global__ __launch_bounds__(256) void im2col_kernel(const float* __restrict__ in,
                                                     unsigned short* __restrict__ Pch) {
    __shared__ unsigned short tile[128 * 128];       // 32 KB, [c][128]
    const int t  = threadIdx.x;
    const int yt = blockIdx.x;                       // 0..27  -> rows 2*yt, 2*yt+1
    const int s  = blockIdx.y;                       // 0..8
    const int b  = blockIdx.z;
    const int kh = s / 3, kw = s - kh * 3;
    const int y0 = yt * 2;

    #pragma unroll
    for (int it = 0; it < 14; it++) {
        const int f = it * 256 + t;
        const int c = f / 28;
        const int rem = f - c * 28;
        const int y = rem / 14;
        const int x4 = rem - y * 14;
        const int yy = y0 + y + kh - 1;
        const int yyc = min(max(yy, 0), HH - 1);
        const bool yok = (yy >= 0) & (yy < HH);
        const float* row = in + ((size_t)(b * IN_C + c)) * NPIX + yyc * WWID;
        unsigned short bf[4];
        #pragma unroll
        for (int e = 0; e < 4; e++) {
            const int xs = x4 * 4 + e + kw - 1;
            const int xc = min(max(xs, 0), WWID - 1);
            float v = row[xc];
            v = (yok & (xs >= 0) & (xs < WWID)) ? v : 0.f;
            bf[e] = f2bf(v);
        }
        const int ppb = (y * WWID + x4 * 4) ^ (((c >> 3) & 15) << 2);
        uint2 pk;
        pk.x = (unsigned)bf[0] | ((unsigned)bf[1] << 16);
        pk.y = (unsigned)bf[2] | ((unsigned)bf[3] << 16);
        *(uint2*)&tile[c * 128 + ppb] = pk;
    }
    __syncthreads();

    #pragma unroll
    for (int it = 0; it < 7; it++) {
        const int ch = it * 256 + t;
        const int oct = ch & 15;
        const int pp = ch >> 4;
        const int sw = oct << 2;
        ushort8 v;
        #pragma unroll
        for (int i = 0; i < 8; i++)
            v[i] = tile[(oct * 8 + i) * 128 + (pp ^ sw)];
        const int p = yt * 112 + pp;
        *(ushort8*)&Pch[((size_t)b * PPAD + p) * KTOT + s * 128 + oct * 8] = v;
    }
}

// ---------- 5) s[b][p][j] = sum_g probs[b,g,p] * r[b,g*8+j] ----------
__global__ __launch_bounds__(256) void s_kernel(const float* __restrict__ Alpha,
                                                const int* __restrict__ mask,
                                                const float* __restrict__ r,
                                                const int* __restrict__ use_alpha,
                                                float* __restrict__ Sws) {
    const int b = blockIdx.y;
    const int p = blockIdx.x * 256 + threadIdx.x;
    __shared__ float rsh[64];
    if (threadIdx.x < 64) rsh[threadIdx.x] = r[b * 64 + threadIdx.x];
    __syncthreads();
    if (p >= PPAD) return;
    float sj[8] = {0, 0, 0, 0, 0, 0, 0, 0};
    if (p < NPIX) {
        float pr[8];
        if (use_alpha[0]) {
            float a[8], m = -1e30f;
            #pragma unroll
            for (int g = 0; g < 8; g++) {
                a[g] = Alpha[((size_t)(b * NG + g)) * NPIX + p];
                m = fmaxf(m, a[g]);
            }
            float sum = 0.f;
            #pragma unroll
            for (int g = 0; g < 8; g++) { pr[g] = expf(a[g] - m); sum += pr[g]; }
            float inv = 1.f / sum;
            #pragma unroll
            for (int g = 0; g < 8; g++) pr[g] *= inv;
        } else {
            int mg = mask[(size_t)b * NPIX + p];
            #pragma unroll
            for (int g = 0; g < 8; g++) pr[g] = (g == mg) ? 1.f : 0.f;
        }
        #pragma unroll
        for (int g = 0; g < 8; g++)
            #pragma unroll
            for (int j = 0; j < 8; j++) sj[j] += pr[g] * rsh[g * 8 + j];
    }
    float* dst = Sws + ((size_t)b * PPAD + p) * 8;
    *(f32x4*)dst = (f32x4){sj[0], sj[1], sj[2], sj[3]};
    *(f32x4*)(dst + 4) = (f32x4){sj[4], sj[5], sj[6], sj[7]};
}

// ---------- 6) main GEMM + blend epilogue ----------
// 1D grid, XCD-pinned swizzle: the 8 mt-blocks of group G=(b,nt) all have
// lid % 8 == G % 8 -> same XCD under round-robin -> B-strip fetched once/L2.
// K-loop: single barrier per iter; prefetch tile k+1 into buf^1 right after
// the barrier so the vmcnt(0) drain at the NEXT barrier lands after a full
// compute phase (load latency hidden).
__global__ __launch_bounds__(256) void gemm_kernel(const unsigned short* __restrict__ Abf,
                                                   const unsigned short* __restrict__ Pch,
                                                   const float* __restrict__ Sws,
                                                   const float* __restrict__ bias,
                                                   float* __restrict__ out) {
    __shared__ __align__(16) unsigned short Ash[2][512 * 8];   // 2 x 8 KB
    __shared__ __align__(16) unsigned short Bsh[2][512 * 8];   // 2 x 8 KB
    const int tid = threadIdx.x;
    const int wv = tid >> 6, ln = tid & 63;
    const int lq = ln >> 4, lr = ln & 15;
    const int wrow = wv >> 1, wcol = wv & 1;

    // swizzled decode
    const int lid = blockIdx.x;            // 0..1599
    const int xcd = lid & 7;
    const int sl  = lid >> 3;              // 0..199
    const int mt  = sl & 7;
    const int G   = (sl >> 3) * 8 + xcd;   // 0..199
    const int b   = G / 25;
    const int nt  = G - b * 25;

    f32x4 acc[4][4];
    #pragma unroll
    for (int i = 0; i < 4; i++)
        #pragma unroll
        for (int j = 0; j < 4; j++) acc[i][j] = (f32x4){0.f, 0.f, 0.f, 0.f};

    const int c0 = tid, c1 = 256 + tid;
    const int q0 = c0 >> 7, r0 = c0 & 127;
    const int q1 = c1 >> 7, r1 = c1 & 127;
    const int br0 = min(nt * 128 + r0, NPIX - 1);
    const int br1 = min(nt * 128 + r1, NPIX - 1);
    const unsigned short* ga0 = Abf + (size_t)(mt * 128 + r0) * KTOT + q0 * 8;
    const unsigned short* ga1 = Abf + (size_t)(mt * 128 + r1) * KTOT + q1 * 8;
    const unsigned short* gb0 = Pch + ((size_t)b * PPAD + br0) * KTOT + q0 * 8;
    const unsigned short* gb1 = Pch + ((size_t)b * PPAD + br1) * KTOT + q1 * 8;
    unsigned short* la0[2] = { &Ash[0][(wv * 64) * 8],       &Ash[1][(wv * 64) * 8] };
    unsigned short* la1[2] = { &Ash[0][(256 + wv * 64) * 8], &Ash[1][(256 + wv * 64) * 8] };
    unsigned short* lb0[2] = { &Bsh[0][(wv * 64) * 8],       &Bsh[1][(wv * 64) * 8] };
    unsigned short* lb1[2] = { &Bsh[0][(256 + wv * 64) * 8], &Bsh[1][(256 + wv * 64) * 8] };

    // prefetch tile 0 into buf 0
    cp16(ga0, la0[0]); cp16(ga1, la1[0]);
    cp16(gb0, lb0[0]); cp16(gb1, lb1[0]);

    int cur = 0;
    for (int kk = 0; kk < KTOT; kk += 32) {
        __syncthreads();                   // drains buf[cur] loads (they had a full compute phase)
        const int nk = kk + 32;
        if (nk < KTOT) {                   // prefetch next tile into buf[cur^1]
            cp16(ga0 + nk, la0[cur ^ 1]); cp16(ga1 + nk, la1[cur ^ 1]);
            cp16(gb0 + nk, lb0[cur ^ 1]); cp16(gb1 + nk, lb1[cur ^ 1]);
        }
        short8 af[4], bfr[4];
        #pragma unroll
        for (int tm = 0; tm < 4; tm++)
            af[tm] = *(const short8*)&Ash[cur][((lq << 7) + wrow * 64 + tm * 16 + lr) * 8];
        #pragma unroll
        for (int tn = 0; tn < 4; tn++)
            bfr[tn] = *(const short8*)&Bsh[cur][((lq << 7) + wcol * 64 + tn * 16 + lr) * 8];
        #pragma unroll
        for (int tm = 0; tm < 4; tm++)
            #pragma unroll
            for (int tn = 0; tn < 4; tn++)
                acc[tm][tn] = __builtin_amdgcn_mfma_f32_16x16x32_bf16(
                    af[tm], bfr[tn], acc[tm][tn], 0, 0, 0);
        cur ^= 1;
    }

    // epilogue: rows m -> j = (lq&1)*4+reg, o_off = lq>>1
    const int j0 = (lq & 1) * 4;
    const int oo = lq >> 1;
    #pragma unroll
    for (int tm = 0; tm < 4; tm++) {
        const int o = mt * 16 + wrow * 8 + tm * 2 + oo;
        const float bo = bias[o];
        #pragma unroll
        for (int tn = 0; tn < 4; tn++) {
            const int p = nt * 128 + wcol * 64 + tn * 16 + lr;
            const f32x4 sv = *(const f32x4*)&Sws[((size_t)b * PPAD + p) * 8 + j0];
            const f32x4 a = acc[tm][tn];
            float part = a.x * sv.x + a.y * sv.y + a.z * sv.z + a.w * sv.w;
            float tot = part + __shfl_xor(part, 16);
            if ((lq & 1) == 0 && p < NPIX)
                out[((size_t)b * OUT_C + o) * NPIX + p] = tot + bo;
        }
    }
}

extern "C" void kernel_launch(void* const* d_in, const int* in_sizes, int n_in,
                              void* d_out, int out_size, void* d_ws, size_t ws_size,
                              hipStream_t stream) {
    const float* inputs = (const float*)d_in[0];
    const int*   mask   = (const int*)d_in[1];
    const float* Alpha  = (const float*)d_in[2];
    const float* wtmpl  = (const float*)d_in[3];
    const float* rw     = (const float*)d_in[4];
    const float* rb     = (const float*)d_in[5];
    const float* bias   = (const float*)d_in[6];
    const int*   ua     = (const int*)d_in[7];
    float* out = (float*)d_out;

    char* ws = (char*)d_ws;
    unsigned short* Pch = (unsigned short*)ws;                   // 8*3200*1152*2 = 58,982,400
    unsigned short* Abf = (unsigned short*)(ws + 58982400);      // 1024*1152*2  =  2,359,296
    float*          Sws = (float*)(ws + 61341696);               // 8*3200*8*4   =    819,200
    float*          xse = (float*)(ws + 62160896);               // 1024*4
    float*          rr  = (float*)(ws + 62164992);               // 512*4

    gap_kernel<<<NB * IN_C, 256, 0, stream>>>(inputs, xse);
    route_kernel<<<NB, 64, 0, stream>>>(xse, rw, rb, rr);
    tconv_kernel<<<576, 256, 0, stream>>>(wtmpl, Abf);
    im2col_kernel<<<dim3(28, 9, NB), 256, 0, stream>>>(inputs, Pch);
    s_kernel<<<dim3(13, NB), 256, 0, stream>>>(Alpha, mask, rr, ua, Sws);
    gemm_kernel<<<1600, 256, 0, stream>>>(Abf, Pch, Sws, bias, out);
}

// Round 4
// 180.326 us; speedup vs baseline: 1.9676x; 1.4921x over previous
//
#include <hip/hip_runtime.h>
#include <stdint.h>

#define IN_C   128
#define OUT_C  128
#define KTOT   1152      // IN_C*3*3
#define NG     8
#define NW     8
#define NB     8
#define HH     56
#define WWID   56
#define NPIX   3136
#define PPAD   3200
#define MTOT   1024      // OUT_C*NW
#define HALO   58        // 56 + zero border on each side
#define HPIX   (HALO*HALO)   // 3364

// k-order is SPATIAL-MAJOR: k' = s*128 + c, s = kh*3+kw.
// B is NOT materialized: gemm gathers from zero-halo Xt[b][58*58][128c] bf16.

typedef __attribute__((ext_vector_type(8))) short short8;
typedef __attribute__((ext_vector_type(8))) unsigned short ushort8;
typedef __attribute__((ext_vector_type(4))) float f32x4;

__device__ __forceinline__ unsigned short f2bf(float f) {
    unsigned u = __float_as_uint(f);
    u += 0x7FFF + ((u >> 16) & 1);          // round-to-nearest-even
    return (unsigned short)(u >> 16);
}

__device__ __forceinline__ void cp16(const unsigned short* g, unsigned short* l) {
    __builtin_amdgcn_global_load_lds(
        (const __attribute__((address_space(1))) unsigned int*)g,
        (__attribute__((address_space(3))) unsigned int*)l,
        16, 0, 0);
}

// ---------- 1) global average pool ----------
__global__ __launch_bounds__(256) void gap_kernel(const float* __restrict__ in,
                                                  float* __restrict__ xse) {
    const int bc = blockIdx.x;                       // 0..1023
    const float* src = in + (size_t)bc * NPIX;
    float s = 0.f;
    for (int i = threadIdx.x; i < NPIX / 4; i += 256) {
        float4 v = ((const float4*)src)[i];
        s += v.x + v.y + v.z + v.w;
    }
    #pragma unroll
    for (int off = 32; off; off >>= 1) s += __shfl_down(s, off);
    __shared__ float ws4[4];
    if ((threadIdx.x & 63) == 0) ws4[threadIdx.x >> 6] = s;
    __syncthreads();
    if (threadIdx.x == 0)
        xse[bc] = (ws4[0] + ws4[1] + ws4[2] + ws4[3]) * (1.0f / (float)NPIX);
}

// ---------- 2) routing: r[b,gj] = 2*sigmoid(xse@W^T + b)/NW ----------
__global__ __launch_bounds__(64) void route_kernel(const float* __restrict__ xse,
                                                   const float* __restrict__ rw,
                                                   const float* __restrict__ rb,
                                                   float* __restrict__ r) {
    const int b = blockIdx.x;
    const int gj = threadIdx.x;                      // 0..63
    __shared__ float xs[IN_C];
    xs[gj] = xse[b * IN_C + gj];
    xs[gj + 64] = xse[b * IN_C + 64 + gj];
    __syncthreads();
    float acc = rb[gj];
    #pragma unroll 8
    for (int c = 0; c < IN_C; c++) acc += xs[c] * rw[gj * IN_C + c];
    r[b * 64 + gj] = 0.25f / (1.0f + expf(-acc));    // 2*sigmoid/8
}

// ---------- 3) templates -> bf16, A[m=o*8+j][k'=s*128+c] = T[(o*1152+c*9+s)*8+j] ----------
__global__ __launch_bounds__(256) void tconv_kernel(const float* __restrict__ T,
                                                    unsigned short* __restrict__ Abf) {
    const int id = blockIdx.x * 256 + threadIdx.x;   // 0..147455 exact (1024 m * 144 kc)
    const int m = id / 144;
    const int kc = id - m * 144;
    const int o = m >> 3, j = m & 7;
    const int s = kc >> 4;
    const int c0 = (kc & 15) << 3;
    ushort8 v;
    #pragma unroll
    for (int i = 0; i < 8; i++)
        v[i] = f2bf(T[((size_t)(o * KTOT + (c0 + i) * 9 + s)) * 8 + j]);
    *(ushort8*)&Abf[(size_t)m * KTOT + s * 128 + c0] = v;
}

// ---------- 4) transpose: in[b][c][y][x] fp32 -> Xt[b][(y+1)*58+(x+1)][c] bf16, zero halo ----------
__global__ __launch_bounds__(256) void transpose_kernel(const float* __restrict__ in,
                                                        unsigned short* __restrict__ Xt) {
    __shared__ unsigned short tile[128 * 128];       // 32 KB, [c][pix 0..112)
    const int t  = threadIdx.x;
    const int yt = blockIdx.x;                       // 0..27 -> input rows 2yt, 2yt+1
    const int b  = blockIdx.y;
    const int y0 = yt * 2;

    // phase 1: 3584 float4 units = 128c * 2y * 14x4 (always in-bounds, no masks)
    #pragma unroll
    for (int it = 0; it < 14; it++) {
        const int f = it * 256 + t;
        const int c = f / 28;
        const int rem = f - c * 28;
        const int y = rem / 14;
        const int x4 = rem - y * 14;
        const float4 v = *(const float4*)(in + ((size_t)(b * IN_C + c)) * NPIX
                                          + (y0 + y) * WWID + x4 * 4);
        unsigned short bf0 = f2bf(v.x), bf1 = f2bf(v.y), bf2 = f2bf(v.z), bf3 = f2bf(v.w);
        const int ppb = (y * WWID + x4 * 4) ^ (((c >> 3) & 15) << 2);
        uint2 pk;
        pk.x = (unsigned)bf0 | ((unsigned)bf1 << 16);
        pk.y = (unsigned)bf2 | ((unsigned)bf3 << 16);
        *(uint2*)&tile[c * 128 + ppb] = pk;
    }
    __syncthreads();

    // phase 2: 1792 chunks = 112 pix * 16 octs -> coalesced 16B stores into halo grid
    #pragma unroll
    for (int it = 0; it < 7; it++) {
        const int ch = it * 256 + t;
        const int oct = ch & 15;
        const int pp = ch >> 4;
        const int sw = oct << 2;
        ushort8 v;
        #pragma unroll
        for (int i = 0; i < 8; i++)
            v[i] = tile[(oct * 8 + i) * 128 + (pp ^ sw)];
        const int y2 = (pp >= WWID) ? 1 : 0;
        const int xg = pp - y2 * WWID;
        const size_t hp = (size_t)b * HPIX + (y0 + y2 + 1) * HALO + (xg + 1);
        *(ushort8*)&Xt[hp * 128 + oct * 8] = v;
    }

    // halo zero: columns xx=0,57 of this block's two rows
    if (t < 64) {
        const int pi = t >> 4, oct = t & 15;
        const int yy = y0 + 1 + (pi >> 1);
        const int xx = (pi & 1) * 57;
        *(ushort8*)&Xt[((size_t)b * HPIX + yy * HALO + xx) * 128 + oct * 8] =
            (ushort8){0, 0, 0, 0, 0, 0, 0, 0};
    }
    // halo zero: full rows yy=0 (yt==0) and yy=57 (yt==27): 58*16 = 928 chunks
    if (yt == 0 || yt == 27) {
        const int yy = (yt == 0) ? 0 : 57;
        #pragma unroll
        for (int it = 0; it < 4; it++) {
            const int ch = it * 256 + t;
            if (ch < 928) {
                const int xx = ch >> 4, oct = ch & 15;
                *(ushort8*)&Xt[((size_t)b * HPIX + yy * HALO + xx) * 128 + oct * 8] =
                    (ushort8){0, 0, 0, 0, 0, 0, 0, 0};
            }
        }
    }
}

// ---------- 5) s[b][p][j] = sum_g probs[b,g,p] * r[b,g*8+j] ----------
__global__ __launch_bounds__(256) void s_kernel(const float* __restrict__ Alpha,
                                                const int* __restrict__ mask,
                                                const float* __restrict__ r,
                                                const int* __restrict__ use_alpha,
                                                float* __restrict__ Sws) {
    const int b = blockIdx.y;
    const int p = blockIdx.x * 256 + threadIdx.x;
    __shared__ float rsh[64];
    if (threadIdx.x < 64) rsh[threadIdx.x] = r[b * 64 + threadIdx.x];
    __syncthreads();
    if (p >= PPAD) return;
    float sj[8] = {0, 0, 0, 0, 0, 0, 0, 0};
    if (p < NPIX) {
        float pr[8];
        if (use_alpha[0]) {
            float a[8], m = -1e30f;
            #pragma unroll
            for (int g = 0; g < 8; g++) {
                a[g] = Alpha[((size_t)(b * NG + g)) * NPIX + p];
                m = fmaxf(m, a[g]);
            }
            float sum = 0.f;
            #pragma unroll
            for (int g = 0; g < 8; g++) { pr[g] = expf(a[g] - m); sum += pr[g]; }
            float inv = 1.f / sum;
            #pragma unroll
            for (int g = 0; g < 8; g++) pr[g] *= inv;
        } else {
            int mg = mask[(size_t)b * NPIX + p];
            #pragma unroll
            for (int g = 0; g < 8; g++) pr[g] = (g == mg) ? 1.f : 0.f;
        }
        #pragma unroll
        for (int g = 0; g < 8; g++)
            #pragma unroll
            for (int j = 0; j < 8; j++) sj[j] += pr[g] * rsh[g * 8 + j];
    }
    float* dst = Sws + ((size_t)b * PPAD + p) * 8;
    *(f32x4*)dst = (f32x4){sj[0], sj[1], sj[2], sj[3]};
    *(f32x4*)(dst + 4) = (f32x4){sj[4], sj[5], sj[6], sj[7]};
}

// ---------- 6) main GEMM + blend epilogue ----------
// XCD pin: b = lid&7 -> per-XCD L2 working set = A(2.4MB) + Xt[b](0.86MB) -> all L2 hits.
// B staged straight from halo Xt with per-lane gather (LDS side stays lane*16-contig).
// Chunk map ch = r*4 + q (q XOR-swizzled by r&3): 4-lane clusters read 64B contiguous.
__global__ __launch_bounds__(256) void gemm_kernel(const unsigned short* __restrict__ Abf,
                                                   const unsigned short* __restrict__ Xt,
                                                   const float* __restrict__ Sws,
                                                   const float* __restrict__ bias,
                                                   float* __restrict__ out) {
    __shared__ __align__(16) unsigned short Ash[2][512 * 8];   // 2 x 8 KB
    __shared__ __align__(16) unsigned short Bsh[2][512 * 8];   // 2 x 8 KB
    const int tid = threadIdx.x;
    const int wv = tid >> 6, ln = tid & 63;
    const int lq = ln >> 4, lr = ln & 15;
    const int wrow = wv >> 1, wcol = wv & 1;

    const int lid = blockIdx.x;            // 0..1599
    const int b   = lid & 7;               // XCD = b
    const int sl  = lid >> 3;              // 0..199
    const int mt  = sl & 7;
    const int nt  = sl >> 3;               // 0..24

    f32x4 acc[4][4];
    #pragma unroll
    for (int i = 0; i < 4; i++)
        #pragma unroll
        for (int j = 0; j < 4; j++) acc[i][j] = (f32x4){0.f, 0.f, 0.f, 0.f};

    // chunk ch = r*4 + qs; global octet q = qs ^ (r&3); issue0: ch=tid, issue1: ch=256+tid
    const int r0 = tid >> 2,  q0 = (tid & 3) ^ (r0 & 3);
    const int r1 = r0 + 64,   q1 = (tid & 3) ^ (r1 & 3);
    // A: row m, 64B c-slice
    const unsigned short* ga0 = Abf + (size_t)(mt * 128 + r0) * KTOT + q0 * 8;
    const unsigned short* ga1 = Abf + (size_t)(mt * 128 + r1) * KTOT + q1 * 8;
    // B: halo pixel base (s=0 -> halo coord (y,x)), c-octet
    const int p0 = min(nt * 128 + r0, NPIX - 1);
    const int p1 = min(nt * 128 + r1, NPIX - 1);
    const int y0p = p0 / WWID, x0p = p0 - y0p * WWID;
    const int y1p = p1 / WWID, x1p = p1 - y1p * WWID;
    const unsigned short* gb0 = Xt + ((size_t)b * HPIX + y0p * HALO + x0p) * 128 + q0 * 8;
    const unsigned short* gb1 = Xt + ((size_t)b * HPIX + y1p * HALO + x1p) * 128 + q1 * 8;

    unsigned short* la0[2] = { &Ash[0][(wv * 64) * 8],       &Ash[1][(wv * 64) * 8] };
    unsigned short* la1[2] = { &Ash[0][(256 + wv * 64) * 8], &Ash[1][(256 + wv * 64) * 8] };
    unsigned short* lb0[2] = { &Bsh[0][(wv * 64) * 8],       &Bsh[1][(wv * 64) * 8] };
    unsigned short* lb1[2] = { &Bsh[0][(256 + wv * 64) * 8], &Bsh[1][(256 + wv * 64) * 8] };

    // prefetch tile 0 into buf 0 (s=0 -> offB=0)
    cp16(ga0, la0[0]); cp16(ga1, la1[0]);
    cp16(gb0, lb0[0]); cp16(gb1, lb1[0]);

    int cur = 0;
    for (int kk = 0; kk < KTOT; kk += 32) {
        __syncthreads();                   // buf[cur] loads had a full compute phase of cover
        const int nk = kk + 32;
        if (nk < KTOT) {
            const int s  = nk >> 7;        // uniform: k-span never crosses a 128 boundary
            const int kh = s / 3, kw = s - 3 * kh;
            const int offB = (kh * HALO + kw) * 128 + (nk & 127);
            cp16(ga0 + nk, la0[cur ^ 1]); cp16(ga1 + nk, la1[cur ^ 1]);
            cp16(gb0 + offB, lb0[cur ^ 1]); cp16(gb1 + offB, lb1[cur ^ 1]);
        }
        short8 af[4], bfr[4];
        #pragma unroll
        for (int tm = 0; tm < 4; tm++) {
            const int row = wrow * 64 + tm * 16 + lr;
            af[tm] = *(const short8*)&Ash[cur][(row * 4 + (lq ^ (lr & 3))) * 8];
        }
        #pragma unroll
        for (int tn = 0; tn < 4; tn++) {
            const int row = wcol * 64 + tn * 16 + lr;
            bfr[tn] = *(const short8*)&Bsh[cur][(row * 4 + (lq ^ (lr & 3))) * 8];
        }
        #pragma unroll
        for (int tm = 0; tm < 4; tm++)
            #pragma unroll
            for (int tn = 0; tn < 4; tn++)
                acc[tm][tn] = __builtin_amdgcn_mfma_f32_16x16x32_bf16(
                    af[tm], bfr[tn], acc[tm][tn], 0, 0, 0);
        cur ^= 1;
    }

    // epilogue: rows m -> j = (lq&1)*4+reg, o_off = lq>>1
    const int j0 = (lq & 1) * 4;
    const int oo = lq >> 1;
    #pragma unroll
    for (int tm = 0; tm < 4; tm++) {
        const int o = mt * 16 + wrow * 8 + tm * 2 + oo;
        const float bo = bias[o];
        #pragma unroll
        for (int tn = 0; tn < 4; tn++) {
            const int p = nt * 128 + wcol * 64 + tn * 16 + lr;
            const f32x4 sv = *(const f32x4*)&Sws[((size_t)b * PPAD + p) * 8 + j0];
            const f32x4 a = acc[tm][tn];
            float part = a.x * sv.x + a.y * sv.y + a.z * sv.z + a.w * sv.w;
            float tot = part + __shfl_xor(part, 16);
            if ((lq & 1) == 0 && p < NPIX)
                out[((size_t)b * OUT_C + o) * NPIX + p] = tot + bo;
        }
    }
}

extern "C" void kernel_launch(void* const* d_in, const int* in_sizes, int n_in,
                              void* d_out, int out_size, void* d_ws, size_t ws_size,
                              hipStream_t stream) {
    const float* inputs = (const float*)d_in[0];
    const int*   mask   = (const int*)d_in[1];
    const float* Alpha  = (const float*)d_in[2];
    const float* wtmpl  = (const float*)d_in[3];
    const float* rw     = (const float*)d_in[4];
    const float* rb     = (const float*)d_in[5];
    const float* bias   = (const float*)d_in[6];
    const int*   ua     = (const int*)d_in[7];
    float* out = (float*)d_out;

    char* ws = (char*)d_ws;
    unsigned short* Xt  = (unsigned short*)ws;                  // 8*3364*128*2 = 6,889,472
    unsigned short* Abf = (unsigned short*)(ws + 6889472);      // 1024*1152*2  = 2,359,296
    float*          Sws = (float*)(ws + 9248768);               // 8*3200*8*4   =   819,200
    float*          xse = (float*)(ws + 10067968);              // 1024*4
    float*          rr  = (float*)(ws + 10072064);              // 512*4

    gap_kernel<<<NB * IN_C, 256, 0, stream>>>(inputs, xse);
    route_kernel<<<NB, 64, 0, stream>>>(xse, rw, rb, rr);
    tconv_kernel<<<576, 256, 0, stream>>>(wtmpl, Abf);
    transpose_kernel<<<dim3(28, NB), 256, 0, stream>>>(inputs, Xt);
    s_kernel<<<dim3(13, NB), 256, 0, stream>>>(Alpha, mask, rr, ua, Sws);
    gemm_kernel<<<1600, 256, 0, stream>>>(Abf, Xt, Sws, bias, out);
}